// Round 8
// baseline (744.046 us; speedup 1.0000x reference)
//
#include <hip/hip_runtime.h>
#include <hip/hip_bf16.h>
#include <cstdint>
#include <cstddef>

// D = 64 hardcoded (in_feats == hidden == 64).
// CSR build assumes N <= 131072 (src fits 17 bits; bucket = dst>>8 < 512)
// and E <= 2048*4096 (pscan vals[] capacity).

#define BN_SHIFT 8              // 256 nodes per bucket
#define BN 256
#define NBK 512                 // max bucket count
#define PCHUNK 4096             // edges per hist/part block
#define PCAP 16                 // LDS bin capacity (overflow -> direct exact-slot write)
#define BCAP 10240              // build LDS edge capacity (mean 8192)

typedef float natf4 __attribute__((ext_vector_type(4)));   // for nontemporal stores

static __device__ __forceinline__ uint32_t f32_to_bf16_bits(float f) {
    uint32_t u = __builtin_bit_cast(uint32_t, f);
    u += 0x7fffu + ((u >> 16) & 1u);   // RNE (no NaNs in this problem)
    return u >> 16;
}

static __device__ __forceinline__ void add_bf16x8(float* acc, uint4 q) {
    uint32_t w0 = q.x, w1 = q.y, w2 = q.z, w3 = q.w;
    acc[0] += __builtin_bit_cast(float, w0 << 16);
    acc[1] += __builtin_bit_cast(float, w0 & 0xffff0000u);
    acc[2] += __builtin_bit_cast(float, w1 << 16);
    acc[3] += __builtin_bit_cast(float, w1 & 0xffff0000u);
    acc[4] += __builtin_bit_cast(float, w2 << 16);
    acc[5] += __builtin_bit_cast(float, w2 & 0xffff0000u);
    acc[6] += __builtin_bit_cast(float, w3 << 16);
    acc[7] += __builtin_bit_cast(float, w3 & 0xffff0000u);
}

// ---------------------------------------------------------------- hist
// Per-block LDS histogram of PCHUNK dsts; dense row write to pcnt. NO global atomics.
__global__ __launch_bounds__(256) void hist_kernel(const int* __restrict__ ei,
                                                   int* __restrict__ pcnt, int E) {
    __shared__ int lc[NBK];
    int tid = threadIdx.x;
    lc[tid] = 0; lc[tid + 256] = 0;
    __syncthreads();

    int e0 = blockIdx.x * PCHUNK;
    int m = min(PCHUNK, E - e0);
    const int* dsts = ei + E + e0;
    if ((((uintptr_t)dsts) & 15) == 0) {
        int m4 = m >> 2;
        for (int t = tid; t < m4; t += 256) {
            int4 d = ((const int4*)dsts)[t];
            atomicAdd(&lc[d.x >> BN_SHIFT], 1);
            atomicAdd(&lc[d.y >> BN_SHIFT], 1);
            atomicAdd(&lc[d.z >> BN_SHIFT], 1);
            atomicAdd(&lc[d.w >> BN_SHIFT], 1);
        }
        for (int i = (m4 << 2) + tid; i < m; i += 256)
            atomicAdd(&lc[dsts[i] >> BN_SHIFT], 1);
    } else {
        for (int i = tid; i < m; i += 256)
            atomicAdd(&lc[dsts[i] >> BN_SHIFT], 1);
    }
    __syncthreads();
    int* row = pcnt + (size_t)blockIdx.x * NBK;
    row[tid] = lc[tid];
    row[tid + 256] = lc[tid + 256];
}

// ---------------------------------------------------------------- pscan
// One block per bucket: exclusive scan of its pcnt column (in place), total -> bcnt.
__global__ __launch_bounds__(256) void pscan_kernel(int* __restrict__ pcnt,
                                                    int* __restrict__ bcnt, int PB) {
    __shared__ int ss[256];
    int b = blockIdx.x;
    int tid = threadIdx.x;
    int iper = (PB + 255) >> 8;          // <= 8 by the E-capacity assumption
    int i0 = tid * iper;
    int i1 = min(PB, i0 + iper);
    int vals[8];
    int s = 0;
    for (int i = i0, k = 0; i < i1; ++i, ++k) {
        vals[k] = pcnt[(size_t)i * NBK + b];
        s += vals[k];
    }
    ss[tid] = s;
    __syncthreads();
    for (int o = 1; o < 256; o <<= 1) {
        int u = (tid >= o) ? ss[tid - o] : 0;
        __syncthreads();
        ss[tid] += u;
        __syncthreads();
    }
    int run = ss[tid] - s;
    for (int i = i0, k = 0; i < i1; ++i, ++k) {
        pcnt[(size_t)i * NBK + b] = run;
        run += vals[k];
    }
    if (tid == 255) bcnt[b] = ss[255];
}

// ---------------------------------------------------------------- bscan (1 block)
__global__ __launch_bounds__(256) void bscan_kernel(const int* __restrict__ bcnt,
                                                    int* __restrict__ bbase) {
    __shared__ int s[256];
    int t = threadIdx.x;
    int c0 = bcnt[2 * t], c1 = bcnt[2 * t + 1];
    int v = c0 + c1;
    s[t] = v;
    __syncthreads();
    for (int off = 1; off < 256; off <<= 1) {
        int u = (t >= off) ? s[t - off] : 0;
        __syncthreads();
        s[t] += u;
        __syncthreads();
    }
    int ex = s[t] - v;
    bbase[2 * t] = ex;
    bbase[2 * t + 1] = ex + c0;
    if (t == 255) bbase[NBK] = ex + c0 + c1;   // == E
}

// ---------------------------------------------------------------- partition
// Deterministic: this block's exact base per bucket = bbase[b] + poff[blk][b].
// pack = src | (dstoff << 17). LDS bins + exact-slot overflow. NO global atomics.
__global__ __launch_bounds__(256) void part_kernel(const int* __restrict__ ei,
                                                   const int* __restrict__ bbase,
                                                   const int* __restrict__ poff,
                                                   uint32_t* __restrict__ stage, int E) {
    __shared__ int cnt[NBK];
    __shared__ int base[NBK];
    __shared__ uint32_t bins[NBK * PCAP];   // 32 KB
    int tid = threadIdx.x;
    cnt[tid] = 0; cnt[tid + 256] = 0;
    {
        const int* prow = poff + (size_t)blockIdx.x * NBK;
        base[tid] = bbase[tid] + prow[tid];
        base[tid + 256] = bbase[tid + 256] + prow[tid + 256];
    }
    __syncthreads();

    int e0 = blockIdx.x * PCHUNK;
#pragma unroll
    for (int k = 0; k < PCHUNK / 256; ++k) {
        int e = e0 + (k << 8) + tid;
        if (e < E) {
            int s = ei[e];
            int d = ei[E + e];
            int b = d >> BN_SHIFT;
            uint32_t pack = (uint32_t)s | ((uint32_t)(d & (BN - 1)) << 17);
            int pos = atomicAdd(&cnt[b], 1);
            if (pos < PCAP) bins[b * PCAP + pos] = pack;
            else stage[base[b] + pos] = pack;     // exact slot, race-free
        }
    }
    __syncthreads();

    // flush: each wave handles 4 bins at a time (16 lanes per bin)
    int wave = tid >> 6, lane = tid & 63;
    int sub = lane >> 4, idx = lane & 15;
    for (int b0 = wave * 4; b0 < NBK; b0 += 16) {
        int b = b0 + sub;
        int c = min(cnt[b], PCAP);
        if (idx < c) stage[base[b] + idx] = bins[b * PCAP + idx];
    }
}

// ---------------------------------------------------------------- build
// One block per bucket. Self-loop folded at slot 0; col holds byte offsets (src*128).
__global__ __launch_bounds__(256) void build_kernel(const uint32_t* __restrict__ stage,
                                                    const int* __restrict__ bbase,
                                                    int* __restrict__ rowptr,
                                                    float* __restrict__ dis,
                                                    int* __restrict__ col, int n) {
    __shared__ uint32_t eb[BCAP];            // 40 KB
    __shared__ int cnt[BN];
    __shared__ int off[BN];
    __shared__ int cur[BN];
    __shared__ int ssum[256];
    int tid = threadIdx.x;
    int b = blockIdx.x;
    int node0 = b << BN_SHIFT;
    int ebase = bbase[b];
    int ecnt = bbase[b + 1] - ebase;
    int colbase = ebase + node0;             // prior buckets' edges + self slots

    cnt[tid] = 0;
    cur[tid] = 0;
    __syncthreads();

    bool fits = (ecnt <= BCAP);
    for (int i = tid; i < ecnt; i += 256) {
        uint32_t pk = stage[ebase + i];
        if (fits) eb[i] = pk;
        atomicAdd(&cnt[pk >> 17], 1);
    }
    __syncthreads();

    int c = cnt[tid] + 1;                    // + self slot
    ssum[tid] = c;
    __syncthreads();
    for (int o = 1; o < 256; o <<= 1) {
        int u = (tid >= o) ? ssum[tid - o] : 0;
        __syncthreads();
        ssum[tid] += u;
        __syncthreads();
    }
    int ex = ssum[tid] - c;
    off[tid] = ex;
    int node = node0 + tid;
    if (node <= n) rowptr[node] = colbase + ex;
    if (node < n) {
        dis[node] = rsqrtf((float)c);        // c = deg+1 (self)
        col[colbase + ex] = node << 7;       // self edge, byte offset
    }
    __syncthreads();

    if (fits) {
        for (int i = tid; i < ecnt; i += 256) {
            uint32_t pk = eb[i];
            int doff = pk >> 17;
            int p = atomicAdd(&cur[doff], 1);
            col[colbase + off[doff] + 1 + p] = (int)(pk & 0x1ffff) << 7;
        }
    } else {
        for (int i = tid; i < ecnt; i += 256) {
            uint32_t pk = stage[ebase + i];
            int doff = pk >> 17;
            int p = atomicAdd(&cur[doff], 1);
            col[colbase + off[doff] + 1 + p] = (int)(pk & 0x1ffff) << 7;
        }
    }
}

// ---------------------------------------------------------------- GEMM [N,64]@[64,64] v5
// W staged in LDS; each thread computes 8 ROWS x 4 COLS (lane map: 16 col-groups x
// 4 row-groups/wave -> 32 rows/wave, 128 rows/block). vs v4 (64 rows/wave): 2x the
// waves (3128 -> ~3/SIMD, was 1.5) for latency hiding AND half the ds_read per wave
// (64 x b128, one per k-step). VALU floor 5.2us, LDS-pipe floor 3.9us. ~120 VGPR.
// Same k-order FMA chain per output -> bit-identical results.
// MODE 0: out = bf16( (x@W) * dis[row] ); also writes a zero row at index n.
// MODE 1: out = fp32( (x@W) + bias )
template <int MODE>
__global__ __launch_bounds__(256) void gemm_kernel(const float* __restrict__ x,
                                                   const float* __restrict__ W,
                                                   const float* __restrict__ dis,
                                                   const float* __restrict__ bias,
                                                   void* __restrict__ out, int n) {
    __shared__ float Wl[64 * 64];
    int t = threadIdx.x;
    {
        const float4* W4 = (const float4*)W;
        float4* Wl4s = (float4*)Wl;
#pragma unroll
        for (int i = 0; i < 4; ++i) Wl4s[t + i * 256] = W4[t + i * 256];
    }
    __syncthreads();

    int cg = t & 15;                     // col group: cols cg*4 .. cg*4+3
    int g = t >> 4;                      // row group: 16 per block, 8 rows each
    int row0 = blockIdx.x * 128 + (g << 3);

    // clamped 32-bit byte offsets for loads; stores predicated on row < n
    const char* xb = (const char*)x;
    uint32_t xo0 = (uint32_t)min(row0 + 0, n - 1) << 8;
    uint32_t xo1 = (uint32_t)min(row0 + 1, n - 1) << 8;
    uint32_t xo2 = (uint32_t)min(row0 + 2, n - 1) << 8;
    uint32_t xo3 = (uint32_t)min(row0 + 3, n - 1) << 8;
    uint32_t xo4 = (uint32_t)min(row0 + 4, n - 1) << 8;
    uint32_t xo5 = (uint32_t)min(row0 + 5, n - 1) << 8;
    uint32_t xo6 = (uint32_t)min(row0 + 6, n - 1) << 8;
    uint32_t xo7 = (uint32_t)min(row0 + 7, n - 1) << 8;

    const float4* wb = ((const float4*)Wl) + cg;   // + k*16 per k-step

    float4 acc[8];
#pragma unroll
    for (int r = 0; r < 8; ++r) acc[r] = make_float4(0.f, 0.f, 0.f, 0.f);

    float4 a0 = *(const float4*)(xb + xo0), a1 = *(const float4*)(xb + xo1);
    float4 a2 = *(const float4*)(xb + xo2), a3 = *(const float4*)(xb + xo3);
    float4 a4 = *(const float4*)(xb + xo4), a5 = *(const float4*)(xb + xo5);
    float4 a6 = *(const float4*)(xb + xo6), a7 = *(const float4*)(xb + xo7);

#define GFMA(r, av)                                                     \
    do {                                                                \
        float xk_ = (kk == 0) ? (av).x : (kk == 1) ? (av).y             \
                  : (kk == 2) ? (av).z : (av).w;                        \
        acc[r].x = fmaf(xk_, w.x, acc[r].x);                            \
        acc[r].y = fmaf(xk_, w.y, acc[r].y);                            \
        acc[r].z = fmaf(xk_, w.z, acc[r].z);                            \
        acc[r].w = fmaf(xk_, w.w, acc[r].w);                            \
    } while (0)

    for (int k4 = 0; k4 < 16; ++k4) {
        float4 n0 = a0, n1 = a1, n2 = a2, n3 = a3;
        float4 n4 = a4, n5 = a5, n6 = a6, n7 = a7;
        if (k4 < 15) {
            uint32_t kb = (uint32_t)(k4 + 1) << 4;
            n0 = *(const float4*)(xb + xo0 + kb);
            n1 = *(const float4*)(xb + xo1 + kb);
            n2 = *(const float4*)(xb + xo2 + kb);
            n3 = *(const float4*)(xb + xo3 + kb);
            n4 = *(const float4*)(xb + xo4 + kb);
            n5 = *(const float4*)(xb + xo5 + kb);
            n6 = *(const float4*)(xb + xo6 + kb);
            n7 = *(const float4*)(xb + xo7 + kb);
        }
#pragma unroll
        for (int kk = 0; kk < 4; ++kk) {
            float4 w = wb[(((k4 << 2) + kk) << 4)];
            GFMA(0, a0); GFMA(1, a1); GFMA(2, a2); GFMA(3, a3);
            GFMA(4, a4); GFMA(5, a5); GFMA(6, a6); GFMA(7, a7);
        }
        a0 = n0; a1 = n1; a2 = n2; a3 = n3;
        a4 = n4; a5 = n5; a6 = n6; a7 = n7;
    }
#undef GFMA

    if (MODE == 0) {
#pragma unroll
        for (int r = 0; r < 8; ++r) {
            int row = row0 + r;
            if (row < n) {
                float s = dis[row];
                float4 A = acc[r];
                uint2 o;
                o.x = (f32_to_bf16_bits(A.y * s) << 16) | f32_to_bf16_bits(A.x * s);
                o.y = (f32_to_bf16_bits(A.w * s) << 16) | f32_to_bf16_bits(A.z * s);
                *(uint2*)((char*)out + (size_t)row * 128 + (cg << 3)) = o;
            } else if (row == n) {
                *(uint2*)((char*)out + (size_t)n * 128 + (cg << 3)) = make_uint2(0u, 0u);
            }
        }
    } else {
        const float4 bb = ((const float4*)bias)[cg];
#pragma unroll
        for (int r = 0; r < 8; ++r) {
            int row = row0 + r;
            if (row < n) {
                float4 A = acc[r];
                A.x += bb.x; A.y += bb.y; A.z += bb.z; A.w += bb.w;
                ((float4*)out)[(size_t)row * 16 + cg] = A;
            }
        }
    }
}

// ---------------------------------------------------------------- pull aggregation
// (R4-best form: 50.6us measured.) 8 lanes per node (lane owns a 16B chunk), 8
// nodes/wave. 8 gathers in flight every round; out-of-range slots redirect
// (v_cndmask) to a zero row at gbuf+n*128. Next-round col offsets prefetched during
// the adds. Nontemporal fp32 stores keep the output from evicting gbuf in L2.
// agg is pinned at ~3.7 TB/s L2-miss service (R3/R4/R5 probes) -- structural floor.
__global__ __launch_bounds__(256) void agg_kernel(const char* __restrict__ g,
                                                  const int* __restrict__ rowptr,
                                                  const int* __restrict__ col,
                                                  const float* __restrict__ dis,
                                                  const float* __restrict__ bias,
                                                  float* __restrict__ out, int n) {
    int t = threadIdx.x;
    int node = (blockIdx.x << 5) + (t >> 3);
    if (node >= n) return;
    int c = t & 7;                     // 16B chunk index: feats c*8 .. c*8+7

    int beg = rowptr[node];
    int m = rowptr[node + 1] - beg;    // >= 1 (self-loop at slot 0)
    float dv = dis[node];

    float acc[8];
#pragma unroll
    for (int j = 0; j < 8; ++j) acc[j] = 0.f;

    const char* gc = g + (c << 4);
    const int* cp = col + beg;         // this node's col slots are contiguous
    const int zoff = n << 7;           // zero row (written by gemm<0>)

    // round-0 offsets (cp overreads <=7 slots stay inside col's +BN slack)
    int c0 = cp[0], c1 = cp[1], c2 = cp[2], c3 = cp[3];
    int c4 = cp[4], c5 = cp[5], c6 = cp[6], c7 = cp[7];
    int o0 = c0;
    int o1 = (1 < m) ? c1 : zoff;
    int o2 = (2 < m) ? c2 : zoff;
    int o3 = (3 < m) ? c3 : zoff;
    int o4 = (4 < m) ? c4 : zoff;
    int o5 = (5 < m) ? c5 : zoff;
    int o6 = (6 < m) ? c6 : zoff;
    int o7 = (7 < m) ? c7 : zoff;

    int i = 0;
    for (;;) {
        uint4 q0 = *(const uint4*)(gc + o0);
        uint4 q1 = *(const uint4*)(gc + o1);
        uint4 q2 = *(const uint4*)(gc + o2);
        uint4 q3 = *(const uint4*)(gc + o3);
        uint4 q4 = *(const uint4*)(gc + o4);
        uint4 q5 = *(const uint4*)(gc + o5);
        uint4 q6 = *(const uint4*)(gc + o6);
        uint4 q7 = *(const uint4*)(gc + o7);
        int i2 = i + 8;
        bool more = (i2 < m);
        if (more) {
            int n0 = cp[i2], n1 = cp[i2 + 1], n2 = cp[i2 + 2], n3 = cp[i2 + 3];
            int n4 = cp[i2 + 4], n5 = cp[i2 + 5], n6 = cp[i2 + 6], n7 = cp[i2 + 7];
            o0 = n0;
            o1 = (i2 + 1 < m) ? n1 : zoff;
            o2 = (i2 + 2 < m) ? n2 : zoff;
            o3 = (i2 + 3 < m) ? n3 : zoff;
            o4 = (i2 + 4 < m) ? n4 : zoff;
            o5 = (i2 + 5 < m) ? n5 : zoff;
            o6 = (i2 + 6 < m) ? n6 : zoff;
            o7 = (i2 + 7 < m) ? n7 : zoff;
        }
        add_bf16x8(acc, q0);
        add_bf16x8(acc, q1);
        add_bf16x8(acc, q2);
        add_bf16x8(acc, q3);
        add_bf16x8(acc, q4);
        add_bf16x8(acc, q5);
        add_bf16x8(acc, q6);
        add_bf16x8(acc, q7);
        i = i2;
        if (!more) break;
    }

    // epilogue: out[node][c*8+j] = relu(acc[j]*dis + bias[c*8+j]); fully coalesced
    const float4* b4 = (const float4*)(bias + (c << 3));
    float4 bb0 = b4[0], bb1 = b4[1];
    natf4 r0, r1;
    r0.x = fmaxf(fmaf(acc[0], dv, bb0.x), 0.f);
    r0.y = fmaxf(fmaf(acc[1], dv, bb0.y), 0.f);
    r0.z = fmaxf(fmaf(acc[2], dv, bb0.z), 0.f);
    r0.w = fmaxf(fmaf(acc[3], dv, bb0.w), 0.f);
    r1.x = fmaxf(fmaf(acc[4], dv, bb1.x), 0.f);
    r1.y = fmaxf(fmaf(acc[5], dv, bb1.y), 0.f);
    r1.z = fmaxf(fmaf(acc[6], dv, bb1.z), 0.f);
    r1.w = fmaxf(fmaf(acc[7], dv, bb1.w), 0.f);
    natf4* op = (natf4*)(out + (size_t)node * 64 + (c << 3));
    __builtin_nontemporal_store(r0, op);
    __builtin_nontemporal_store(r1, op + 1);
}

// ---------------------------------------------------------------- launch
extern "C" void kernel_launch(void* const* d_in, const int* in_sizes, int n_in,
                              void* d_out, int out_size, void* d_ws, size_t ws_size,
                              hipStream_t stream) {
    const float* x  = (const float*)d_in[0];
    const int*   ei = (const int*)d_in[1];
    const float* W1 = (const float*)d_in[2];
    const float* b1 = (const float*)d_in[3];
    const float* W2 = (const float*)d_in[4];
    const float* b2 = (const float*)d_in[5];
    // Wq/bq/Wk/bk dead: softmax over a length-1 axis is identity.
    const float* Wv = (const float*)d_in[10];
    const float* bv = (const float*)d_in[11];

    const int N = in_sizes[0] / 64;
    const int E = in_sizes[1] / 2;
    const int NB = (N + BN - 1) >> BN_SHIFT;
    const int PB = (E + PCHUNK - 1) / PCHUNK;

    auto align_up = [](size_t v) { return (v + 255) & ~(size_t)255; };
    char* p = (char*)d_ws;
    int*   rowptr = (int*)p;    p += align_up((size_t)(N + 1) * 4);
    float* dis    = (float*)p;  p += align_up((size_t)N * 4);
    int*   pcnt   = (int*)p;    p += align_up((size_t)PB * NBK * 4);
    int*   bcnt   = (int*)p;    p += align_up((size_t)NBK * 4);
    int*   bbase  = (int*)p;    p += align_up((size_t)(NBK + 1) * 4);
    int*   col    = (int*)p;    p += align_up((size_t)(E + N + BN) * 4);
    size_t gsz    = (size_t)(N + 1) * 128 > (size_t)E * 4 ? (size_t)(N + 1) * 128
                                                          : (size_t)E * 4 + 128;
    char*  gbuf   = p;          p += align_up(gsz);              // bf16 rows + zero row
    float* xbuf   = (float*)p;  p += align_up((size_t)N * 256);  // fp32 hidden
    uint32_t* stage = (uint32_t*)gbuf;   // dead before first gemm writes gbuf

    int nbl = (N + 128) >> 7;  // 128 rows/block; covers rows 0..N (row N = zero row)
    int abl = (N + 31) / 32;   // 8 nodes per wave, 32 per block

    hist_kernel<<<PB, 256, 0, stream>>>(ei, pcnt, E);
    pscan_kernel<<<NBK, 256, 0, stream>>>(pcnt, bcnt, PB);
    bscan_kernel<<<1, 256, 0, stream>>>(bcnt, bbase);
    part_kernel<<<PB, 256, 0, stream>>>(ei, bbase, pcnt, stage, E);
    build_kernel<<<NB, 256, 0, stream>>>(stage, bbase, rowptr, dis, col, N);

    // layer 1: g = bf16(dis * (x@W1)); xbuf = relu(dis*Agg(g) + b1)
    gemm_kernel<0><<<nbl, 256, 0, stream>>>(x, W1, dis, nullptr, gbuf, N);
    agg_kernel<<<abl, 256, 0, stream>>>(gbuf, rowptr, col, dis, b1, xbuf, N);

    // layer 2
    gemm_kernel<0><<<nbl, 256, 0, stream>>>(xbuf, W2, dis, nullptr, gbuf, N);
    agg_kernel<<<abl, 256, 0, stream>>>(gbuf, rowptr, col, dis, b2, xbuf, N);

    // output: v = xbuf@Wv + bv (attention identity at seq_len 1)
    gemm_kernel<1><<<nbl, 256, 0, stream>>>(xbuf, Wv, nullptr, bv, d_out, N);
}

// Round 9
// 317.917 us; speedup vs baseline: 2.3404x; 2.3404x over previous
//
#include <hip/hip_runtime.h>
#include <hip/hip_bf16.h>
#include <cstdint>
#include <cstddef>

// D = 64 hardcoded (in_feats == hidden == 64).
// CSR build assumes N <= 131072 (src fits 17 bits; bucket = dst>>8 < 512)
// and E <= 2048*4096 (pscan vals[] capacity).

#define BN_SHIFT 8              // 256 nodes per bucket
#define BN 256
#define NBK 512                 // max bucket count
#define PCHUNK 4096             // edges per hist/part block
#define PCAP 16                 // LDS bin capacity (overflow -> direct exact-slot write)
#define BCAP 10240              // build LDS edge capacity (mean 8192)

typedef float natf4 __attribute__((ext_vector_type(4)));   // for nontemporal stores

static __device__ __forceinline__ uint32_t f32_to_bf16_bits(float f) {
    uint32_t u = __builtin_bit_cast(uint32_t, f);
    u += 0x7fffu + ((u >> 16) & 1u);   // RNE (no NaNs in this problem)
    return u >> 16;
}

static __device__ __forceinline__ void add_bf16x8(float* acc, uint4 q) {
    uint32_t w0 = q.x, w1 = q.y, w2 = q.z, w3 = q.w;
    acc[0] += __builtin_bit_cast(float, w0 << 16);
    acc[1] += __builtin_bit_cast(float, w0 & 0xffff0000u);
    acc[2] += __builtin_bit_cast(float, w1 << 16);
    acc[3] += __builtin_bit_cast(float, w1 & 0xffff0000u);
    acc[4] += __builtin_bit_cast(float, w2 << 16);
    acc[5] += __builtin_bit_cast(float, w2 & 0xffff0000u);
    acc[6] += __builtin_bit_cast(float, w3 << 16);
    acc[7] += __builtin_bit_cast(float, w3 & 0xffff0000u);
}

// ---------------------------------------------------------------- hist
// Per-block LDS histogram of PCHUNK dsts; dense row write to pcnt. NO global atomics.
__global__ __launch_bounds__(256) void hist_kernel(const int* __restrict__ ei,
                                                   int* __restrict__ pcnt, int E) {
    __shared__ int lc[NBK];
    int tid = threadIdx.x;
    lc[tid] = 0; lc[tid + 256] = 0;
    __syncthreads();

    int e0 = blockIdx.x * PCHUNK;
    int m = min(PCHUNK, E - e0);
    const int* dsts = ei + E + e0;
    if ((((uintptr_t)dsts) & 15) == 0) {
        int m4 = m >> 2;
        for (int t = tid; t < m4; t += 256) {
            int4 d = ((const int4*)dsts)[t];
            atomicAdd(&lc[d.x >> BN_SHIFT], 1);
            atomicAdd(&lc[d.y >> BN_SHIFT], 1);
            atomicAdd(&lc[d.z >> BN_SHIFT], 1);
            atomicAdd(&lc[d.w >> BN_SHIFT], 1);
        }
        for (int i = (m4 << 2) + tid; i < m; i += 256)
            atomicAdd(&lc[dsts[i] >> BN_SHIFT], 1);
    } else {
        for (int i = tid; i < m; i += 256)
            atomicAdd(&lc[dsts[i] >> BN_SHIFT], 1);
    }
    __syncthreads();
    int* row = pcnt + (size_t)blockIdx.x * NBK;
    row[tid] = lc[tid];
    row[tid + 256] = lc[tid + 256];
}

// ---------------------------------------------------------------- pscan
// One block per bucket: exclusive scan of its pcnt column (in place), total -> bcnt.
__global__ __launch_bounds__(256) void pscan_kernel(int* __restrict__ pcnt,
                                                    int* __restrict__ bcnt, int PB) {
    __shared__ int ss[256];
    int b = blockIdx.x;
    int tid = threadIdx.x;
    int iper = (PB + 255) >> 8;          // <= 8 by the E-capacity assumption
    int i0 = tid * iper;
    int i1 = min(PB, i0 + iper);
    int vals[8];
    int s = 0;
    for (int i = i0, k = 0; i < i1; ++i, ++k) {
        vals[k] = pcnt[(size_t)i * NBK + b];
        s += vals[k];
    }
    ss[tid] = s;
    __syncthreads();
    for (int o = 1; o < 256; o <<= 1) {
        int u = (tid >= o) ? ss[tid - o] : 0;
        __syncthreads();
        ss[tid] += u;
        __syncthreads();
    }
    int run = ss[tid] - s;
    for (int i = i0, k = 0; i < i1; ++i, ++k) {
        pcnt[(size_t)i * NBK + b] = run;
        run += vals[k];
    }
    if (tid == 255) bcnt[b] = ss[255];
}

// ---------------------------------------------------------------- bscan (1 block)
__global__ __launch_bounds__(256) void bscan_kernel(const int* __restrict__ bcnt,
                                                    int* __restrict__ bbase) {
    __shared__ int s[256];
    int t = threadIdx.x;
    int c0 = bcnt[2 * t], c1 = bcnt[2 * t + 1];
    int v = c0 + c1;
    s[t] = v;
    __syncthreads();
    for (int off = 1; off < 256; off <<= 1) {
        int u = (t >= off) ? s[t - off] : 0;
        __syncthreads();
        s[t] += u;
        __syncthreads();
    }
    int ex = s[t] - v;
    bbase[2 * t] = ex;
    bbase[2 * t + 1] = ex + c0;
    if (t == 255) bbase[NBK] = ex + c0 + c1;   // == E
}

// ---------------------------------------------------------------- partition
// Deterministic: this block's exact base per bucket = bbase[b] + poff[blk][b].
// pack = src | (dstoff << 17). LDS bins + exact-slot overflow. NO global atomics.
__global__ __launch_bounds__(256) void part_kernel(const int* __restrict__ ei,
                                                   const int* __restrict__ bbase,
                                                   const int* __restrict__ poff,
                                                   uint32_t* __restrict__ stage, int E) {
    __shared__ int cnt[NBK];
    __shared__ int base[NBK];
    __shared__ uint32_t bins[NBK * PCAP];   // 32 KB
    int tid = threadIdx.x;
    cnt[tid] = 0; cnt[tid + 256] = 0;
    {
        const int* prow = poff + (size_t)blockIdx.x * NBK;
        base[tid] = bbase[tid] + prow[tid];
        base[tid + 256] = bbase[tid + 256] + prow[tid + 256];
    }
    __syncthreads();

    int e0 = blockIdx.x * PCHUNK;
#pragma unroll
    for (int k = 0; k < PCHUNK / 256; ++k) {
        int e = e0 + (k << 8) + tid;
        if (e < E) {
            int s = ei[e];
            int d = ei[E + e];
            int b = d >> BN_SHIFT;
            uint32_t pack = (uint32_t)s | ((uint32_t)(d & (BN - 1)) << 17);
            int pos = atomicAdd(&cnt[b], 1);
            if (pos < PCAP) bins[b * PCAP + pos] = pack;
            else stage[base[b] + pos] = pack;     // exact slot, race-free
        }
    }
    __syncthreads();

    // flush: each wave handles 4 bins at a time (16 lanes per bin)
    int wave = tid >> 6, lane = tid & 63;
    int sub = lane >> 4, idx = lane & 15;
    for (int b0 = wave * 4; b0 < NBK; b0 += 16) {
        int b = b0 + sub;
        int c = min(cnt[b], PCAP);
        if (idx < c) stage[base[b] + idx] = bins[b * PCAP + idx];
    }
}

// ---------------------------------------------------------------- build
// One block per bucket. Self-loop folded at slot 0; col holds byte offsets (src*128).
__global__ __launch_bounds__(256) void build_kernel(const uint32_t* __restrict__ stage,
                                                    const int* __restrict__ bbase,
                                                    int* __restrict__ rowptr,
                                                    float* __restrict__ dis,
                                                    int* __restrict__ col, int n) {
    __shared__ uint32_t eb[BCAP];            // 40 KB
    __shared__ int cnt[BN];
    __shared__ int off[BN];
    __shared__ int cur[BN];
    __shared__ int ssum[256];
    int tid = threadIdx.x;
    int b = blockIdx.x;
    int node0 = b << BN_SHIFT;
    int ebase = bbase[b];
    int ecnt = bbase[b + 1] - ebase;
    int colbase = ebase + node0;             // prior buckets' edges + self slots

    cnt[tid] = 0;
    cur[tid] = 0;
    __syncthreads();

    bool fits = (ecnt <= BCAP);
    for (int i = tid; i < ecnt; i += 256) {
        uint32_t pk = stage[ebase + i];
        if (fits) eb[i] = pk;
        atomicAdd(&cnt[pk >> 17], 1);
    }
    __syncthreads();

    int c = cnt[tid] + 1;                    // + self slot
    ssum[tid] = c;
    __syncthreads();
    for (int o = 1; o < 256; o <<= 1) {
        int u = (tid >= o) ? ssum[tid - o] : 0;
        __syncthreads();
        ssum[tid] += u;
        __syncthreads();
    }
    int ex = ssum[tid] - c;
    off[tid] = ex;
    int node = node0 + tid;
    if (node <= n) rowptr[node] = colbase + ex;
    if (node < n) {
        dis[node] = rsqrtf((float)c);        // c = deg+1 (self)
        col[colbase + ex] = node << 7;       // self edge, byte offset
    }
    __syncthreads();

    if (fits) {
        for (int i = tid; i < ecnt; i += 256) {
            uint32_t pk = eb[i];
            int doff = pk >> 17;
            int p = atomicAdd(&cur[doff], 1);
            col[colbase + off[doff] + 1 + p] = (int)(pk & 0x1ffff) << 7;
        }
    } else {
        for (int i = tid; i < ecnt; i += 256) {
            uint32_t pk = stage[ebase + i];
            int doff = pk >> 17;
            int p = atomicAdd(&cur[doff], 1);
            col[colbase + off[doff] + 1 + p] = (int)(pk & 0x1ffff) << 7;
        }
    }
}

// ---------------------------------------------------------------- GEMM [N,64]@[64,64] v6
// EXACT v4 structure (R7-proven: no spill, 36us) with ONE change: 4 rows per thread
// instead of 8 -> 128 rows/block, 2x the waves (3136 ~= 3.1/SIMD, was 1.5) to hide
// the x-load latency that capped v4. Per-thread live state halves (16 float4), so
// spill risk is strictly lower than v4. Pointer addressing and k-order FMA chain
// unchanged -> bit-identical results. (v5's byte-offset + small-body rewrite spilled
// to scratch: VGPR 256, 208MB scratch writes, 175us -- reverted.)
// MODE 0: out = bf16( (x@W) * dis[row] ); also writes a zero row at index n.
// MODE 1: out = fp32( (x@W) + bias )
template <int MODE>
__global__ __launch_bounds__(256) void gemm_kernel(const float* __restrict__ x,
                                                   const float* __restrict__ W,
                                                   const float* __restrict__ dis,
                                                   const float* __restrict__ bias,
                                                   void* __restrict__ out, int n) {
    __shared__ float Wl[64 * 64];
    int t = threadIdx.x;
    {
        const float4* W4 = (const float4*)W;
        float4* Wl4s = (float4*)Wl;
#pragma unroll
        for (int i = 0; i < 4; ++i) Wl4s[t + i * 256] = W4[t + i * 256];
    }
    __syncthreads();

    int cg = t & 7;                      // col group: cols cg*8 .. cg*8+7
    int g = t >> 3;                      // row group: 32 per block, 4 rows each
    int row0 = blockIdx.x * 128 + (g << 2);

    // clamped row pointers for loads; stores predicated on row < n
    const float4* xp0 = (const float4*)(x + (size_t)min(row0 + 0, n - 1) * 64);
    const float4* xp1 = (const float4*)(x + (size_t)min(row0 + 1, n - 1) * 64);
    const float4* xp2 = (const float4*)(x + (size_t)min(row0 + 2, n - 1) * 64);
    const float4* xp3 = (const float4*)(x + (size_t)min(row0 + 3, n - 1) * 64);

    const float4* wb = ((const float4*)Wl) + (cg << 1);   // + k*16 per k

    float4 acc[4][2];
#pragma unroll
    for (int r = 0; r < 4; ++r) {
        acc[r][0] = make_float4(0.f, 0.f, 0.f, 0.f);
        acc[r][1] = make_float4(0.f, 0.f, 0.f, 0.f);
    }

    float4 a0 = xp0[0], a1 = xp1[0], a2 = xp2[0], a3 = xp3[0];

#define GFMA(r, av)                                                     \
    do {                                                                \
        float xk_ = (kk == 0) ? (av).x : (kk == 1) ? (av).y             \
                  : (kk == 2) ? (av).z : (av).w;                        \
        acc[r][0].x = fmaf(xk_, w0.x, acc[r][0].x);                     \
        acc[r][0].y = fmaf(xk_, w0.y, acc[r][0].y);                     \
        acc[r][0].z = fmaf(xk_, w0.z, acc[r][0].z);                     \
        acc[r][0].w = fmaf(xk_, w0.w, acc[r][0].w);                     \
        acc[r][1].x = fmaf(xk_, w1.x, acc[r][1].x);                     \
        acc[r][1].y = fmaf(xk_, w1.y, acc[r][1].y);                     \
        acc[r][1].z = fmaf(xk_, w1.z, acc[r][1].z);                     \
        acc[r][1].w = fmaf(xk_, w1.w, acc[r][1].w);                     \
    } while (0)

    for (int k4 = 0; k4 < 16; ++k4) {
        float4 n0 = a0, n1 = a1, n2 = a2, n3 = a3;
        if (k4 < 15) {
            n0 = xp0[k4 + 1]; n1 = xp1[k4 + 1]; n2 = xp2[k4 + 1]; n3 = xp3[k4 + 1];
        }
#pragma unroll
        for (int kk = 0; kk < 4; ++kk) {
            const float4* wr = wb + (((k4 << 2) + kk) << 4);
            float4 w0 = wr[0];
            float4 w1 = wr[1];
            GFMA(0, a0); GFMA(1, a1); GFMA(2, a2); GFMA(3, a3);
        }
        a0 = n0; a1 = n1; a2 = n2; a3 = n3;
    }
#undef GFMA

    if (MODE == 0) {
        uint4 z = make_uint4(0u, 0u, 0u, 0u);
#pragma unroll
        for (int r = 0; r < 4; ++r) {
            int row = row0 + r;
            if (row < n) {
                float s = dis[row];
                float4 A = acc[r][0];
                float4 B = acc[r][1];
                uint4 o;
                o.x = (f32_to_bf16_bits(A.y * s) << 16) | f32_to_bf16_bits(A.x * s);
                o.y = (f32_to_bf16_bits(A.w * s) << 16) | f32_to_bf16_bits(A.z * s);
                o.z = (f32_to_bf16_bits(B.y * s) << 16) | f32_to_bf16_bits(B.x * s);
                o.w = (f32_to_bf16_bits(B.w * s) << 16) | f32_to_bf16_bits(B.z * s);
                *(uint4*)((char*)out + (size_t)row * 128 + (cg << 4)) = o;
            } else if (row == n) {
                *(uint4*)((char*)out + (size_t)n * 128 + (cg << 4)) = z;
            }
        }
    } else {
        const float4* b4 = ((const float4*)bias) + (cg << 1);
        float4 bb0 = b4[0], bb1 = b4[1];
#pragma unroll
        for (int r = 0; r < 4; ++r) {
            int row = row0 + r;
            if (row < n) {
                float4 A = acc[r][0];
                float4 B = acc[r][1];
                A.x += bb0.x; A.y += bb0.y; A.z += bb0.z; A.w += bb0.w;
                B.x += bb1.x; B.y += bb1.y; B.z += bb1.z; B.w += bb1.w;
                float4* fo = (float4*)out + (size_t)row * 16 + (cg << 1);
                fo[0] = A;
                fo[1] = B;
            }
        }
    }
}

// ---------------------------------------------------------------- pull aggregation
// (R4-best form: 50.6us measured.) 8 lanes per node (lane owns a 16B chunk), 8
// nodes/wave. 8 gathers in flight every round; out-of-range slots redirect
// (v_cndmask) to a zero row at gbuf+n*128. Next-round col offsets prefetched during
// the adds. Nontemporal fp32 stores keep the output from evicting gbuf in L2.
// agg is pinned at ~3.7 TB/s L2-miss service (R3/R4/R5 probes) -- structural floor.
__global__ __launch_bounds__(256) void agg_kernel(const char* __restrict__ g,
                                                  const int* __restrict__ rowptr,
                                                  const int* __restrict__ col,
                                                  const float* __restrict__ dis,
                                                  const float* __restrict__ bias,
                                                  float* __restrict__ out, int n) {
    int t = threadIdx.x;
    int node = (blockIdx.x << 5) + (t >> 3);
    if (node >= n) return;
    int c = t & 7;                     // 16B chunk index: feats c*8 .. c*8+7

    int beg = rowptr[node];
    int m = rowptr[node + 1] - beg;    // >= 1 (self-loop at slot 0)
    float dv = dis[node];

    float acc[8];
#pragma unroll
    for (int j = 0; j < 8; ++j) acc[j] = 0.f;

    const char* gc = g + (c << 4);
    const int* cp = col + beg;         // this node's col slots are contiguous
    const int zoff = n << 7;           // zero row (written by gemm<0>)

    // round-0 offsets (cp overreads <=7 slots stay inside col's +BN slack)
    int c0 = cp[0], c1 = cp[1], c2 = cp[2], c3 = cp[3];
    int c4 = cp[4], c5 = cp[5], c6 = cp[6], c7 = cp[7];
    int o0 = c0;
    int o1 = (1 < m) ? c1 : zoff;
    int o2 = (2 < m) ? c2 : zoff;
    int o3 = (3 < m) ? c3 : zoff;
    int o4 = (4 < m) ? c4 : zoff;
    int o5 = (5 < m) ? c5 : zoff;
    int o6 = (6 < m) ? c6 : zoff;
    int o7 = (7 < m) ? c7 : zoff;

    int i = 0;
    for (;;) {
        uint4 q0 = *(const uint4*)(gc + o0);
        uint4 q1 = *(const uint4*)(gc + o1);
        uint4 q2 = *(const uint4*)(gc + o2);
        uint4 q3 = *(const uint4*)(gc + o3);
        uint4 q4 = *(const uint4*)(gc + o4);
        uint4 q5 = *(const uint4*)(gc + o5);
        uint4 q6 = *(const uint4*)(gc + o6);
        uint4 q7 = *(const uint4*)(gc + o7);
        int i2 = i + 8;
        bool more = (i2 < m);
        if (more) {
            int n0 = cp[i2], n1 = cp[i2 + 1], n2 = cp[i2 + 2], n3 = cp[i2 + 3];
            int n4 = cp[i2 + 4], n5 = cp[i2 + 5], n6 = cp[i2 + 6], n7 = cp[i2 + 7];
            o0 = n0;
            o1 = (i2 + 1 < m) ? n1 : zoff;
            o2 = (i2 + 2 < m) ? n2 : zoff;
            o3 = (i2 + 3 < m) ? n3 : zoff;
            o4 = (i2 + 4 < m) ? n4 : zoff;
            o5 = (i2 + 5 < m) ? n5 : zoff;
            o6 = (i2 + 6 < m) ? n6 : zoff;
            o7 = (i2 + 7 < m) ? n7 : zoff;
        }
        add_bf16x8(acc, q0);
        add_bf16x8(acc, q1);
        add_bf16x8(acc, q2);
        add_bf16x8(acc, q3);
        add_bf16x8(acc, q4);
        add_bf16x8(acc, q5);
        add_bf16x8(acc, q6);
        add_bf16x8(acc, q7);
        i = i2;
        if (!more) break;
    }

    // epilogue: out[node][c*8+j] = relu(acc[j]*dis + bias[c*8+j]); fully coalesced
    const float4* b4 = (const float4*)(bias + (c << 3));
    float4 bb0 = b4[0], bb1 = b4[1];
    natf4 r0, r1;
    r0.x = fmaxf(fmaf(acc[0], dv, bb0.x), 0.f);
    r0.y = fmaxf(fmaf(acc[1], dv, bb0.y), 0.f);
    r0.z = fmaxf(fmaf(acc[2], dv, bb0.z), 0.f);
    r0.w = fmaxf(fmaf(acc[3], dv, bb0.w), 0.f);
    r1.x = fmaxf(fmaf(acc[4], dv, bb1.x), 0.f);
    r1.y = fmaxf(fmaf(acc[5], dv, bb1.y), 0.f);
    r1.z = fmaxf(fmaf(acc[6], dv, bb1.z), 0.f);
    r1.w = fmaxf(fmaf(acc[7], dv, bb1.w), 0.f);
    natf4* op = (natf4*)(out + (size_t)node * 64 + (c << 3));
    __builtin_nontemporal_store(r0, op);
    __builtin_nontemporal_store(r1, op + 1);
}

// ---------------------------------------------------------------- launch
extern "C" void kernel_launch(void* const* d_in, const int* in_sizes, int n_in,
                              void* d_out, int out_size, void* d_ws, size_t ws_size,
                              hipStream_t stream) {
    const float* x  = (const float*)d_in[0];
    const int*   ei = (const int*)d_in[1];
    const float* W1 = (const float*)d_in[2];
    const float* b1 = (const float*)d_in[3];
    const float* W2 = (const float*)d_in[4];
    const float* b2 = (const float*)d_in[5];
    // Wq/bq/Wk/bk dead: softmax over a length-1 axis is identity.
    const float* Wv = (const float*)d_in[10];
    const float* bv = (const float*)d_in[11];

    const int N = in_sizes[0] / 64;
    const int E = in_sizes[1] / 2;
    const int NB = (N + BN - 1) >> BN_SHIFT;
    const int PB = (E + PCHUNK - 1) / PCHUNK;

    auto align_up = [](size_t v) { return (v + 255) & ~(size_t)255; };
    char* p = (char*)d_ws;
    int*   rowptr = (int*)p;    p += align_up((size_t)(N + 1) * 4);
    float* dis    = (float*)p;  p += align_up((size_t)N * 4);
    int*   pcnt   = (int*)p;    p += align_up((size_t)PB * NBK * 4);
    int*   bcnt   = (int*)p;    p += align_up((size_t)NBK * 4);
    int*   bbase  = (int*)p;    p += align_up((size_t)(NBK + 1) * 4);
    int*   col    = (int*)p;    p += align_up((size_t)(E + N + BN) * 4);
    size_t gsz    = (size_t)(N + 1) * 128 > (size_t)E * 4 ? (size_t)(N + 1) * 128
                                                          : (size_t)E * 4 + 128;
    char*  gbuf   = p;          p += align_up(gsz);              // bf16 rows + zero row
    float* xbuf   = (float*)p;  p += align_up((size_t)N * 256);  // fp32 hidden
    uint32_t* stage = (uint32_t*)gbuf;   // dead before first gemm writes gbuf

    int nbl = (N + 128) >> 7;  // 128 rows/block; covers rows 0..N (row N = zero row)
    int abl = (N + 31) / 32;   // 8 nodes per wave, 32 per block

    hist_kernel<<<PB, 256, 0, stream>>>(ei, pcnt, E);
    pscan_kernel<<<NBK, 256, 0, stream>>>(pcnt, bcnt, PB);
    bscan_kernel<<<1, 256, 0, stream>>>(bcnt, bbase);
    part_kernel<<<PB, 256, 0, stream>>>(ei, bbase, pcnt, stage, E);
    build_kernel<<<NB, 256, 0, stream>>>(stage, bbase, rowptr, dis, col, N);

    // layer 1: g = bf16(dis * (x@W1)); xbuf = relu(dis*Agg(g) + b1)
    gemm_kernel<0><<<nbl, 256, 0, stream>>>(x, W1, dis, nullptr, gbuf, N);
    agg_kernel<<<abl, 256, 0, stream>>>(gbuf, rowptr, col, dis, b1, xbuf, N);

    // layer 2
    gemm_kernel<0><<<nbl, 256, 0, stream>>>(xbuf, W2, dis, nullptr, gbuf, N);
    agg_kernel<<<abl, 256, 0, stream>>>(gbuf, rowptr, col, dis, b2, xbuf, N);

    // output: v = xbuf@Wv + bv (attention identity at seq_len 1)
    gemm_kernel<1><<<nbl, 256, 0, stream>>>(xbuf, Wv, nullptr, bv, d_out, N);
}